// Round 14
// baseline (857.626 us; speedup 1.0000x reference)
//
#include <hip/hip_runtime.h>

// WaveInputEncoder on MI355X — round 14.
// vs r13: gemm128_k bumped to 5 blocks/CU (__launch_bounds__(256,5); 5x32KB
// = 160KB LDS pool exactly) and block mapping reverted to r12's mb-fast
// compact per-XCD band (lowest measured FETCH). Everything else identical.

typedef __attribute__((ext_vector_type(8))) short s16x8;
typedef __attribute__((ext_vector_type(4))) short s16x4;
typedef __attribute__((ext_vector_type(4))) float f32x4;

__device__ __forceinline__ short f2bf(float x){
  unsigned u = __float_as_uint(x);
  unsigned r = (u + 0x7fffu + ((u >> 16) & 1u)) >> 16;   // RNE
  return (short)r;
}
__device__ __forceinline__ float bf2f(short x){
  return __uint_as_float(((unsigned)(unsigned short)x) << 16);
}
__device__ __forceinline__ void gload16(const void* g, void* l){
  __builtin_amdgcn_global_load_lds((const __attribute__((address_space(1))) void*)g,
                                   (__attribute__((address_space(3))) void*)l, 16, 0, 0);
}
__device__ __forceinline__ float gelu_f(float v){
  float u2 = v * (0.7978845608f + 0.0356774081f * v * v);
  float e = __expf(2.0f * u2);
  float th = 1.0f - 2.0f / (e + 1.0f);
  return 0.5f * v * (1.0f + th);
}

// ---------------- prep: DFT tables + (block 511) softplus/rot consts ----------------
__global__ __launch_bounds__(256) void prep_tab_k(float* __restrict__ ctab, float* __restrict__ stab,
    const float* __restrict__ mw, const float* __restrict__ po, float* __restrict__ wcs){
  int idx = blockIdx.x * 256 + threadIdx.x;      // idx = m*4096 + t
  int m = idx >> 12, t = idx & 4095;
  int r = (m * t) & 4095;
  float ang = (float)r * 1.5339807878856412e-3f; // 2*pi/4096
  float s, c; sincosf(ang, &s, &c);
  ctab[idx] = c; stab[idx] = s;
  if (blockIdx.x == 511 && threadIdx.x < 32){
    int i = threadIdx.x;
    wcs[i]      = log1pf(expf(mw[i]));
    wcs[32 + i] = cosf(po[i]);
    wcs[64 + i] = sinf(po[i]);
  }
}

// transpose fp32 (R x C) -> bf16 (C x R), 64x64 LDS tiles
__global__ __launch_bounds__(256) void transpose_bf16_k(const float* __restrict__ src,
                                                        short* __restrict__ dst,
                                                        int R, int C){
  __shared__ float tile[64][65];
  int c0 = blockIdx.x * 64, r0 = blockIdx.y * 64;
  for (int i = 0; i < 16; ++i){
    int idx = i * 256 + threadIdx.x;
    int rr = idx >> 6, cc = idx & 63;
    tile[rr][cc] = src[(size_t)(r0 + rr) * C + c0 + cc];
  }
  __syncthreads();
  for (int i = 0; i < 16; ++i){
    int idx = i * 256 + threadIdx.x;
    int cc = idx >> 6, rr = idx & 63;
    dst[(size_t)(c0 + cc) * R + r0 + rr] = f2bf(tile[rr][cc]);
  }
}

// ---------------- kernel A3: embed + rotate + FTE + positional phase ----------------
__global__ __launch_bounds__(256) void kernelA3(const int* __restrict__ tokens,
    const float* __restrict__ frw, const float* __restrict__ fiw,
    const float* __restrict__ wcs, const float* __restrict__ ftew,
    const float* __restrict__ fteb, const float* __restrict__ posph,
    float* __restrict__ xout){
  __shared__ float ffs[64][8];
  __shared__ float last[8][256];
  __shared__ float wsh[96];
  int tid = threadIdx.x;
  int b = blockIdx.x >> 9, t0 = (blockIdx.x & 511) * 8;
  if (tid < 96) wsh[tid] = wcs[tid];
  __syncthreads();
  {
    int j = tid >> 5, m = tid & 31;          // 8 tok x 32 m
    int tok = tokens[b * 4096 + t0 + j];
    float w = wsh[m];
    float re = frw[(size_t)tok * 32 + m] * w;
    float im = fiw[(size_t)tok * 32 + m] * w;
    float c = wsh[32 + m], s = wsh[64 + m];
    ffs[m][j]      = re * c - im * s;        // real_rot
    ffs[32 + m][j] = re * s + im * c;        // imag_rot
  }
  __syncthreads();
  const int d0 = tid * 4;
  f32x4 bb = *(const f32x4*)&fteb[d0];
  float a[8][4];
  #pragma unroll
  for (int j = 0; j < 8; ++j)
    #pragma unroll
    for (int e = 0; e < 4; ++e) a[j][e] = bb[e];
  #pragma unroll 4
  for (int k = 0; k < 64; ++k){
    f32x4 wv = *(const f32x4*)&ftew[k * 1024 + d0];
    f32x4 f0 = *(const f32x4*)&ffs[k][0];
    f32x4 f1 = *(const f32x4*)&ffs[k][4];
    #pragma unroll
    for (int j = 0; j < 4; ++j)
      #pragma unroll
      for (int e = 0; e < 4; ++e){
        a[j][e]     += f0[j] * wv[e];
        a[4 + j][e] += f1[j] * wv[e];
      }
  }
  #pragma unroll
  for (int j = 0; j < 8; ++j) last[j][tid] = a[j][3];
  __syncthreads();
  const int tm1 = (tid + 255) & 255;          // d0-1 (wraps 0 -> 1023)
  #pragma unroll
  for (int j = 0; j < 8; ++j){
    float pm1[4];
    pm1[0] = last[j][tm1];
    pm1[1] = a[j][0]; pm1[2] = a[j][1]; pm1[3] = a[j][2];
    f32x4 pp4 = *(const f32x4*)&posph[(size_t)(t0 + j) * 1024 + d0];
    f32x4 o;
    #pragma unroll
    for (int e = 0; e < 4; ++e){
      float pp = pp4[e];
      float p2 = pp * pp;
      float sp = pp * (1.0f - p2 * (1.0f/6.0f) + p2 * p2 * (1.0f/120.0f));
      float cp = 1.0f - p2 * 0.5f + p2 * p2 * (1.0f/24.0f);
      o[e] = a[j][e] * cp + pm1[e] * sp;
    }
    *(f32x4*)&xout[((size_t)b * 4096 + t0 + j) * 1024 + d0] = o;
  }
}

// ---------------- kernel B: truncated forward DFT via rotation recurrence ----------------
__global__ __launch_bounds__(256) void kernelB2(const float* __restrict__ xin,
    float* __restrict__ Pr, float* __restrict__ Pi){
  __shared__ float xsh[64][32];
  int tid = threadIdx.x;
  int bx = blockIdx.x;
  int b = bx >> 8, dch = (bx >> 3) & 31, tc = bx & 7;
  int d0 = dch * 32;
  int t_start = tc * 512;
  int dg = tid >> 5, m = tid & 31;
  const float TPN = 1.5339807878856412e-3f;
  int r0 = (m * t_start) & 4095;
  float cw, sw; sincosf(-(float)r0 * TPN, &sw, &cw);
  float cs, ss; sincosf(-(float)m * TPN, &ss, &cs);
  float ar[4] = {0,0,0,0}, ai[4] = {0,0,0,0};
  for (int t0 = t_start; t0 < t_start + 512; t0 += 64){
    __syncthreads();
    #pragma unroll
    for (int i = 0; i < 2; ++i){
      int unit = i * 256 + tid;
      int tt = unit >> 3, du = (unit & 7) * 4;
      *(f32x4*)&xsh[tt][du] = *(const f32x4*)&xin[((size_t)b * 4096 + t0 + tt) * 1024 + d0 + du];
    }
    __syncthreads();
    #pragma unroll 4
    for (int tt = 0; tt < 64; ++tt){
      f32x4 xv = *(const f32x4*)&xsh[tt][dg * 4];
      #pragma unroll
      for (int j = 0; j < 4; ++j){ ar[j] += xv[j] * cw; ai[j] += xv[j] * sw; }
      float cn = cw * cs - sw * ss;
      sw = cw * ss + sw * cs; cw = cn;
    }
  }
  #pragma unroll
  for (int j = 0; j < 4; ++j){
    int d = d0 + dg * 4 + j;
    size_t idx = (((size_t)tc * 4 + b) * 1024 + d) * 32 + m;
    Pr[idx] = ar[j]; Pi[idx] = ai[j];
  }
}

// ---------------- kernel C (with fused tc-reduction of Pr/Pi) ----------------
__global__ __launch_bounds__(128) void kernelC2(const float* __restrict__ Pr, const float* __restrict__ Pi,
    const float* __restrict__ awr, const float* __restrict__ awi,
    float* __restrict__ Or, float* __restrict__ Oi){
  __shared__ float xr_s[4][128], xi_s[4][128];
  int nm = blockIdx.x; int n = nm >> 5, m = nm & 31;
  int i = threadIdx.x;
  #pragma unroll
  for (int b = 0; b < 4; ++b){
    float sr = 0.0f, si = 0.0f;
    #pragma unroll
    for (int tc = 0; tc < 8; ++tc){
      size_t idx = (((size_t)tc * 4 + b) * 1024 + n * 128 + i) * 32 + m;
      sr += Pr[idx]; si += Pi[idx];
    }
    xr_s[b][i] = sr * 0.015625f; xi_s[b][i] = si * 0.015625f;
  }
  __syncthreads();
  float accr[4] = {0,0,0,0}, acci[4] = {0,0,0,0};
  size_t wb = (((size_t)n * 32 + m) * 128 + i) * 128;
  for (int j = 0; j < 128; ++j){
    float wr = awr[wb + j], wi = awi[wb + j];
    #pragma unroll
    for (int b = 0; b < 4; ++b){
      accr[b] += wr * xr_s[b][j] - wi * xi_s[b][j];
      acci[b] += wr * xi_s[b][j] + wi * xr_s[b][j];
    }
  }
  #pragma unroll
  for (int b = 0; b < 4; ++b){
    float vr = accr[b], vi = acci[b];
    vr = vr > 0.01f ? vr - 0.01f : (vr < -0.01f ? vr + 0.01f : 0.0f);
    vi = vi > 0.01f ? vi - 0.01f : (vi < -0.01f ? vi + 0.01f : 0.0f);
    size_t dst = ((size_t)b * 32 + m) * 1024 + n * 128 + i;  // [b][m][d]
    Or[dst] = vr; Oi[dst] = vi;
  }
}

// ---------------- kernel D3: d-chunked irfft + residual in-place ----------------
__global__ __launch_bounds__(256) void kernelD3(const float* __restrict__ Or, const float* __restrict__ Oi,
    const float* __restrict__ ctab, const float* __restrict__ stab, float* __restrict__ y){
  __shared__ float cts[32][64], sts[32][64];
  __shared__ float Ors[32][144], Ois[32][144];
  int tid = threadIdx.x;
  int bx = blockIdx.x;
  int b = bx >> 9, tc = (bx >> 3) & 63, dc = bx & 7;
  int t0 = tc * 64, d0 = dc * 128;
  for (int i = 0; i < 8; ++i){
    int lin = i * 256 + tid;
    int m = lin >> 6, tl = lin & 63;
    float f = (m == 0 ? 1.0f : 2.0f) * 0.015625f;
    cts[m][tl] = ctab[m * 4096 + t0 + tl] * f;
    sts[m][tl] = stab[m * 4096 + t0 + tl] * f;
  }
  for (int i = 0; i < 4; ++i){
    int lin = i * 256 + tid;
    int m = lin >> 5, q = lin & 31;
    int w = q * 4;
    int ph = w + ((w >> 5) << 2);
    size_t src = ((size_t)b * 32 + m) * 1024 + d0 + w;
    *(f32x4*)&Ors[m][ph] = *(const f32x4*)&Or[src];
    *(f32x4*)&Ois[m][ph] = *(const f32x4*)&Oi[src];
  }
  __syncthreads();
  int tt = tid >> 4, dl = tid & 15;
  int wb0 = dl * 8;
  int ph0 = wb0 + ((wb0 >> 5) << 2);
  int ph1 = ph0 + 4;
  float acc[4][8];
  #pragma unroll
  for (int q = 0; q < 4; ++q)
    #pragma unroll
    for (int j = 0; j < 8; ++j) acc[q][j] = 0.f;
  for (int m = 0; m < 32; ++m){
    f32x4 cv = *(const f32x4*)&cts[m][tt * 4];
    f32x4 sv = *(const f32x4*)&sts[m][tt * 4];
    f32x4 orv0 = *(const f32x4*)&Ors[m][ph0];
    f32x4 orv1 = *(const f32x4*)&Ors[m][ph1];
    f32x4 oiv0 = *(const f32x4*)&Ois[m][ph0];
    f32x4 oiv1 = *(const f32x4*)&Ois[m][ph1];
    #pragma unroll
    for (int q = 0; q < 4; ++q){
      #pragma unroll
      for (int e = 0; e < 4; ++e){
        acc[q][e]     += cv[q] * orv0[e] - sv[q] * oiv0[e];
        acc[q][4 + e] += cv[q] * orv1[e] - sv[q] * oiv1[e];
      }
    }
  }
  #pragma unroll
  for (int q = 0; q < 4; ++q){
    size_t row = ((size_t)b * 4096 + t0 + tt * 4 + q) * 1024 + d0 + dl * 8;
    f32x4 r0 = *(const f32x4*)&y[row];
    f32x4 r1 = *(const f32x4*)&y[row + 4];
    #pragma unroll
    for (int e = 0; e < 4; ++e){ r0[e] += acc[q][e]; r1[e] += acc[q][4 + e]; }
    *(f32x4*)&y[row] = r0;
    *(f32x4*)&y[row + 4] = r1;
  }
}

// ---------------- LN1: y (f32) -> xln1 (bf16) ----------------
__global__ __launch_bounds__(256) void ln1_k(const float* __restrict__ y,
    const float* __restrict__ g, const float* __restrict__ bb, short* __restrict__ xln){
  size_t row = blockIdx.x;
  int tid = threadIdx.x;
  f32x4 v = *(const f32x4*)(y + row * 1024 + tid * 4);
  float sum = v[0] + v[1] + v[2] + v[3];
  float sq  = v[0]*v[0] + v[1]*v[1] + v[2]*v[2] + v[3]*v[3];
  for (int off = 32; off; off >>= 1){ sum += __shfl_down(sum, off); sq += __shfl_down(sq, off); }
  __shared__ float rs[4], rq[4];
  int lane = tid & 63, w = tid >> 6;
  if (lane == 0){ rs[w] = sum; rq[w] = sq; }
  __syncthreads();
  sum = rs[0] + rs[1] + rs[2] + rs[3]; sq = rq[0] + rq[1] + rq[2] + rq[3];
  float mu = sum * (1.0f / 1024.0f);
  float var = sq * (1.0f / 1024.0f) - mu * mu;
  float sc = rsqrtf(var + 1e-5f);
  s16x4 o;
  #pragma unroll
  for (int j = 0; j < 4; ++j){
    int d = tid * 4 + j;
    o[j] = f2bf((v[j] - mu) * sc * g[d] + bb[d]);
  }
  *(s16x4*)(xln + row * 1024 + tid * 4) = o;
}

// ---------------- m97-style 128^2 high-TLP bf16 MFMA GEMM ----------------
// 256 thr / 4 waves (2x2), BK=64 single-buffered 32KB LDS, 5 blocks/CU
// (5 x 32KB = 160KB LDS pool). mb-fast compact per-XCD band (r12 mapping,
// lowest measured FETCH). 0-conflict swizzle (r7-verified).
template<int EPI>
__global__ __launch_bounds__(256, 5) void gemm128_k(const short* __restrict__ A,
    const short* __restrict__ BT, const float* __restrict__ bias,
    const short* __restrict__ resid, short* __restrict__ Hout,
    float* __restrict__ Fout, int K, int N, int nMB, long row0_abs){
  __shared__ __align__(16) short As[8192];
  __shared__ __align__(16) short Bs[8192];
  const int tid = threadIdx.x;
  const int lane = tid & 63, wv = tid >> 6;
  const int wr = wv >> 1, wc = wv & 1;
  const int lr = lane & 15, lg = lane >> 4;

  // compact per-XCD band mapping (mb-fast, r12)
  const int xcd = blockIdx.x & 7, l = blockIdx.x >> 3;
  const int mband = nMB >> 3;
  const int mb = xcd * mband + (l % mband);
  const int nb = l / mband;
  const long arow0 = (long)mb * 128;
  const long bcol0 = (long)nb * 128;
  const int NT = K >> 6;

  const int rr = tid >> 3;
  const int sl8 = ((tid & 7) ^ (rr & 7)) * 8;
  const long aoff = (long)rr * K + sl8;
  const short* Au = A  + arow0 * K;
  const short* Bu = BT + bcol0 * K;
  const int ldsw = wv * 512;

  const int aR = (wr * 64 + lr) * 64;
  const int bR = (wc * 64 + lr) * 64;
  const int asl0 = ((lg)     ^ (lr & 7)) * 8;
  const int asl1 = ((4 + lg) ^ (lr & 7)) * 8;

  f32x4 acc[4][4] = {};

  for (int t = 0; t < NT; ++t){
    const long kof = (long)t * 64;
    #pragma unroll
    for (int u = 0; u < 4; ++u)
      gload16(Au + (long)(u * 32) * K + kof + aoff, As + u * 2048 + ldsw);
    #pragma unroll
    for (int u = 0; u < 4; ++u)
      gload16(Bu + (long)(u * 32) * K + kof + aoff, Bs + u * 2048 + ldsw);
    __syncthreads();
    #pragma unroll
    for (int ks = 0; ks < 2; ++ks){
      const int so = ks ? asl1 : asl0;
      s16x8 af[4], bf[4];
      #pragma unroll
      for (int mi = 0; mi < 4; ++mi) af[mi] = *(const s16x8*)&As[aR + mi * 1024 + so];
      #pragma unroll
      for (int ni = 0; ni < 4; ++ni) bf[ni] = *(const s16x8*)&Bs[bR + ni * 1024 + so];
      #pragma unroll
      for (int mi = 0; mi < 4; ++mi)
        #pragma unroll
        for (int ni = 0; ni < 4; ++ni)
          acc[mi][ni] = __builtin_amdgcn_mfma_f32_16x16x32_bf16(af[mi], bf[ni], acc[mi][ni], 0, 0, 0);
    }
    __syncthreads();
  }

  const int rb = lg * 4;
  #pragma unroll
  for (int mi = 0; mi < 4; ++mi){
    #pragma unroll
    for (int ni = 0; ni < 4; ++ni){
      int cl = (int)bcol0 + wc * 64 + ni * 16 + lr;
      float bv = bias[cl];
      #pragma unroll
      for (int i = 0; i < 4; ++i){
        long rl = arow0 + wr * 64 + mi * 16 + rb + i;
        float v = acc[mi][ni][i] + bv;
        if constexpr (EPI == 0){
          Hout[rl * (long)N + cl] = f2bf(gelu_f(v));
        } else {
          float rv = bf2f(resid[(row0_abs + rl) * 1024 + cl]);
          Fout[(row0_abs + rl) * 1024 + cl] = v + rv;
        }
      }
    }
  }
}

// ---------------- LN2 in-place on f32 out ----------------
__global__ __launch_bounds__(256) void ln2_k(float* __restrict__ out,
    const float* __restrict__ g, const float* __restrict__ bb){
  size_t row = blockIdx.x;
  int tid = threadIdx.x;
  float* p = out + row * 1024;
  f32x4 v = *(const f32x4*)(p + tid * 4);
  float sum = v[0] + v[1] + v[2] + v[3];
  float sq  = v[0]*v[0] + v[1]*v[1] + v[2]*v[2] + v[3]*v[3];
  for (int off = 32; off; off >>= 1){ sum += __shfl_down(sum, off); sq += __shfl_down(sq, off); }
  __shared__ float rs[4], rq[4];
  int lane = tid & 63, w = tid >> 6;
  if (lane == 0){ rs[w] = sum; rq[w] = sq; }
  __syncthreads();
  sum = rs[0] + rs[1] + rs[2] + rs[3]; sq = rq[0] + rq[1] + rq[2] + rq[3];
  float mu = sum * (1.0f / 1024.0f);
  float var = sq * (1.0f / 1024.0f) - mu * mu;
  float sc = rsqrtf(var + 1e-5f);
  f32x4 o;
  #pragma unroll
  for (int j = 0; j < 4; ++j){
    int d = tid * 4 + j;
    o[j] = (v[j] - mu) * sc * g[d] + bb[d];
  }
  *(f32x4*)(p + tid * 4) = o;
}

// ---------------- launch ----------------
extern "C" void kernel_launch(void* const* d_in, const int* in_sizes, int n_in,
                              void* d_out, int out_size, void* d_ws, size_t ws_size,
                              hipStream_t stream){
  (void)in_sizes; (void)n_in; (void)out_size;
  const int*   tokens = (const int*)d_in[0];
  const float* frw  = (const float*)d_in[1];
  const float* fiw  = (const float*)d_in[2];
  const float* mw   = (const float*)d_in[3];
  const float* po   = (const float*)d_in[4];
  const float* ftew = (const float*)d_in[5];
  const float* fteb = (const float*)d_in[6];
  const float* posph= (const float*)d_in[7];
  const float* awr  = (const float*)d_in[8];
  const float* awi  = (const float*)d_in[9];
  const float* ln1g = (const float*)d_in[10];
  const float* ln1b = (const float*)d_in[11];
  const float* w1   = (const float*)d_in[12];
  const float* b1   = (const float*)d_in[13];
  const float* w2   = (const float*)d_in[14];
  const float* b2   = (const float*)d_in[15];
  const float* ln2g = (const float*)d_in[16];
  const float* ln2b = (const float*)d_in[17];
  float* out = (float*)d_out;

  const size_t HB_BIG   = (size_t)16384 * 4096 * 2;   // 134.2 MB full-M hbuf
  const size_t HB_SMALL = (size_t)16384 * 1024 * 4;   // 67.1 MB (residual-sized)
  const size_t TAIL = (size_t)16384 * 1024 * 2        // xln1
                    + 2 * (size_t)4096 * 1024 * 2     // w1b, w2b
                    + 4 * 524288                      // ctab, stab, Or, Oi
                    + 2 * 4194304                     // Pr, Pi
                    + 512;                            // wcs
  const bool big = ws_size >= HB_BIG + TAIL;
  const size_t hb = big ? HB_BIG : HB_SMALL;

  char* ws = (char*)d_ws;
  size_t o = 0;
  float* residual = (float*)(ws + o); o += hb;        // head doubles as hbuf
  short* hbuf     = (short*)residual;
  short* xln1     = (short*)(ws + o); o += (size_t)16384 * 1024 * 2;
  short* w1b      = (short*)(ws + o); o += (size_t)4096 * 1024 * 2;
  short* w2b      = (short*)(ws + o); o += (size_t)4096 * 1024 * 2;
  float* ctab     = (float*)(ws + o); o += 524288;
  float* stab     = (float*)(ws + o); o += 524288;
  float* Or       = (float*)(ws + o); o += 524288;
  float* Oi       = (float*)(ws + o); o += 524288;
  float* Pr       = (float*)(ws + o); o += 4194304;
  float* Pi       = (float*)(ws + o); o += 4194304;
  float* wcs      = (float*)(ws + o); o += 512;

  prep_tab_k<<<512, 256, 0, stream>>>(ctab, stab, mw, po, wcs);
  transpose_bf16_k<<<dim3(64, 16), 256, 0, stream>>>(w1, w1b, 1024, 4096);
  transpose_bf16_k<<<dim3(16, 64), 256, 0, stream>>>(w2, w2b, 4096, 1024);

  kernelA3<<<2048, 256, 0, stream>>>(tokens, frw, fiw, wcs, ftew, fteb, posph, residual);
  kernelB2<<<1024, 256, 0, stream>>>(residual, Pr, Pi);
  kernelC2<<<256, 128, 0, stream>>>(Pr, Pi, awr, awi, Or, Oi);
  kernelD3<<<2048, 256, 0, stream>>>(Or, Oi, ctab, stab, residual);
  ln1_k<<<16384, 256, 0, stream>>>(residual, ln1g, ln1b, xln1);

  if (big){
    gemm128_k<0><<<4096, 256, 0, stream>>>(xln1, w1b, b1, nullptr, hbuf, nullptr,
                                           1024, 4096, 128, 0);
    gemm128_k<1><<<1024, 256, 0, stream>>>(hbuf, w2b, b2, xln1, nullptr, out,
                                           4096, 1024, 128, 0);
  } else {
    for (int c = 0; c < 2; ++c){
      long row0 = (long)c * 8192;
      gemm128_k<0><<<2048, 256, 0, stream>>>(xln1 + row0 * 1024, w1b, b1, nullptr,
                                             hbuf, nullptr, 1024, 4096, 64, 0);
      gemm128_k<1><<<512, 256, 0, stream>>>(hbuf, w2b, b2, xln1, nullptr, out,
                                            4096, 1024, 64, row0);
    }
  }
  ln2_k<<<16384, 256, 0, stream>>>(out, ln2g, ln2b);
}

// Round 15
// 515.319 us; speedup vs baseline: 1.6643x; 1.6643x over previous
//
#include <hip/hip_runtime.h>

// WaveInputEncoder on MI355X — round 15.
// vs r14: REVERT the (256,5) launch bound (VGPR squeezed to 48 -> acc spilled,
// WRITE_SIZE ~930MB, 380us/dispatch). Back to (256,4) [r12/r13-proven] with
// r12's mb-fast compact per-XCD band mapping (lowest FETCH at equal dur).
// Everything else identical to r13.

typedef __attribute__((ext_vector_type(8))) short s16x8;
typedef __attribute__((ext_vector_type(4))) short s16x4;
typedef __attribute__((ext_vector_type(4))) float f32x4;

__device__ __forceinline__ short f2bf(float x){
  unsigned u = __float_as_uint(x);
  unsigned r = (u + 0x7fffu + ((u >> 16) & 1u)) >> 16;   // RNE
  return (short)r;
}
__device__ __forceinline__ float bf2f(short x){
  return __uint_as_float(((unsigned)(unsigned short)x) << 16);
}
__device__ __forceinline__ void gload16(const void* g, void* l){
  __builtin_amdgcn_global_load_lds((const __attribute__((address_space(1))) void*)g,
                                   (__attribute__((address_space(3))) void*)l, 16, 0, 0);
}
__device__ __forceinline__ float gelu_f(float v){
  float u2 = v * (0.7978845608f + 0.0356774081f * v * v);
  float e = __expf(2.0f * u2);
  float th = 1.0f - 2.0f / (e + 1.0f);
  return 0.5f * v * (1.0f + th);
}

// ---------------- prep: DFT tables + (block 511) softplus/rot consts ----------------
__global__ __launch_bounds__(256) void prep_tab_k(float* __restrict__ ctab, float* __restrict__ stab,
    const float* __restrict__ mw, const float* __restrict__ po, float* __restrict__ wcs){
  int idx = blockIdx.x * 256 + threadIdx.x;      // idx = m*4096 + t
  int m = idx >> 12, t = idx & 4095;
  int r = (m * t) & 4095;
  float ang = (float)r * 1.5339807878856412e-3f; // 2*pi/4096
  float s, c; sincosf(ang, &s, &c);
  ctab[idx] = c; stab[idx] = s;
  if (blockIdx.x == 511 && threadIdx.x < 32){
    int i = threadIdx.x;
    wcs[i]      = log1pf(expf(mw[i]));
    wcs[32 + i] = cosf(po[i]);
    wcs[64 + i] = sinf(po[i]);
  }
}

// transpose fp32 (R x C) -> bf16 (C x R), 64x64 LDS tiles
__global__ __launch_bounds__(256) void transpose_bf16_k(const float* __restrict__ src,
                                                        short* __restrict__ dst,
                                                        int R, int C){
  __shared__ float tile[64][65];
  int c0 = blockIdx.x * 64, r0 = blockIdx.y * 64;
  for (int i = 0; i < 16; ++i){
    int idx = i * 256 + threadIdx.x;
    int rr = idx >> 6, cc = idx & 63;
    tile[rr][cc] = src[(size_t)(r0 + rr) * C + c0 + cc];
  }
  __syncthreads();
  for (int i = 0; i < 16; ++i){
    int idx = i * 256 + threadIdx.x;
    int cc = idx >> 6, rr = idx & 63;
    dst[(size_t)(c0 + cc) * R + r0 + rr] = f2bf(tile[rr][cc]);
  }
}

// ---------------- kernel A3: embed + rotate + FTE + positional phase ----------------
__global__ __launch_bounds__(256) void kernelA3(const int* __restrict__ tokens,
    const float* __restrict__ frw, const float* __restrict__ fiw,
    const float* __restrict__ wcs, const float* __restrict__ ftew,
    const float* __restrict__ fteb, const float* __restrict__ posph,
    float* __restrict__ xout){
  __shared__ float ffs[64][8];
  __shared__ float last[8][256];
  __shared__ float wsh[96];
  int tid = threadIdx.x;
  int b = blockIdx.x >> 9, t0 = (blockIdx.x & 511) * 8;
  if (tid < 96) wsh[tid] = wcs[tid];
  __syncthreads();
  {
    int j = tid >> 5, m = tid & 31;          // 8 tok x 32 m
    int tok = tokens[b * 4096 + t0 + j];
    float w = wsh[m];
    float re = frw[(size_t)tok * 32 + m] * w;
    float im = fiw[(size_t)tok * 32 + m] * w;
    float c = wsh[32 + m], s = wsh[64 + m];
    ffs[m][j]      = re * c - im * s;        // real_rot
    ffs[32 + m][j] = re * s + im * c;        // imag_rot
  }
  __syncthreads();
  const int d0 = tid * 4;
  f32x4 bb = *(const f32x4*)&fteb[d0];
  float a[8][4];
  #pragma unroll
  for (int j = 0; j < 8; ++j)
    #pragma unroll
    for (int e = 0; e < 4; ++e) a[j][e] = bb[e];
  #pragma unroll 4
  for (int k = 0; k < 64; ++k){
    f32x4 wv = *(const f32x4*)&ftew[k * 1024 + d0];
    f32x4 f0 = *(const f32x4*)&ffs[k][0];
    f32x4 f1 = *(const f32x4*)&ffs[k][4];
    #pragma unroll
    for (int j = 0; j < 4; ++j)
      #pragma unroll
      for (int e = 0; e < 4; ++e){
        a[j][e]     += f0[j] * wv[e];
        a[4 + j][e] += f1[j] * wv[e];
      }
  }
  #pragma unroll
  for (int j = 0; j < 8; ++j) last[j][tid] = a[j][3];
  __syncthreads();
  const int tm1 = (tid + 255) & 255;          // d0-1 (wraps 0 -> 1023)
  #pragma unroll
  for (int j = 0; j < 8; ++j){
    float pm1[4];
    pm1[0] = last[j][tm1];
    pm1[1] = a[j][0]; pm1[2] = a[j][1]; pm1[3] = a[j][2];
    f32x4 pp4 = *(const f32x4*)&posph[(size_t)(t0 + j) * 1024 + d0];
    f32x4 o;
    #pragma unroll
    for (int e = 0; e < 4; ++e){
      float pp = pp4[e];
      float p2 = pp * pp;
      float sp = pp * (1.0f - p2 * (1.0f/6.0f) + p2 * p2 * (1.0f/120.0f));
      float cp = 1.0f - p2 * 0.5f + p2 * p2 * (1.0f/24.0f);
      o[e] = a[j][e] * cp + pm1[e] * sp;
    }
    *(f32x4*)&xout[((size_t)b * 4096 + t0 + j) * 1024 + d0] = o;
  }
}

// ---------------- kernel B: truncated forward DFT via rotation recurrence ----------------
__global__ __launch_bounds__(256) void kernelB2(const float* __restrict__ xin,
    float* __restrict__ Pr, float* __restrict__ Pi){
  __shared__ float xsh[64][32];
  int tid = threadIdx.x;
  int bx = blockIdx.x;
  int b = bx >> 8, dch = (bx >> 3) & 31, tc = bx & 7;
  int d0 = dch * 32;
  int t_start = tc * 512;
  int dg = tid >> 5, m = tid & 31;
  const float TPN = 1.5339807878856412e-3f;
  int r0 = (m * t_start) & 4095;
  float cw, sw; sincosf(-(float)r0 * TPN, &sw, &cw);
  float cs, ss; sincosf(-(float)m * TPN, &ss, &cs);
  float ar[4] = {0,0,0,0}, ai[4] = {0,0,0,0};
  for (int t0 = t_start; t0 < t_start + 512; t0 += 64){
    __syncthreads();
    #pragma unroll
    for (int i = 0; i < 2; ++i){
      int unit = i * 256 + tid;
      int tt = unit >> 3, du = (unit & 7) * 4;
      *(f32x4*)&xsh[tt][du] = *(const f32x4*)&xin[((size_t)b * 4096 + t0 + tt) * 1024 + d0 + du];
    }
    __syncthreads();
    #pragma unroll 4
    for (int tt = 0; tt < 64; ++tt){
      f32x4 xv = *(const f32x4*)&xsh[tt][dg * 4];
      #pragma unroll
      for (int j = 0; j < 4; ++j){ ar[j] += xv[j] * cw; ai[j] += xv[j] * sw; }
      float cn = cw * cs - sw * ss;
      sw = cw * ss + sw * cs; cw = cn;
    }
  }
  #pragma unroll
  for (int j = 0; j < 4; ++j){
    int d = d0 + dg * 4 + j;
    size_t idx = (((size_t)tc * 4 + b) * 1024 + d) * 32 + m;
    Pr[idx] = ar[j]; Pi[idx] = ai[j];
  }
}

// ---------------- kernel C (with fused tc-reduction of Pr/Pi) ----------------
__global__ __launch_bounds__(128) void kernelC2(const float* __restrict__ Pr, const float* __restrict__ Pi,
    const float* __restrict__ awr, const float* __restrict__ awi,
    float* __restrict__ Or, float* __restrict__ Oi){
  __shared__ float xr_s[4][128], xi_s[4][128];
  int nm = blockIdx.x; int n = nm >> 5, m = nm & 31;
  int i = threadIdx.x;
  #pragma unroll
  for (int b = 0; b < 4; ++b){
    float sr = 0.0f, si = 0.0f;
    #pragma unroll
    for (int tc = 0; tc < 8; ++tc){
      size_t idx = (((size_t)tc * 4 + b) * 1024 + n * 128 + i) * 32 + m;
      sr += Pr[idx]; si += Pi[idx];
    }
    xr_s[b][i] = sr * 0.015625f; xi_s[b][i] = si * 0.015625f;
  }
  __syncthreads();
  float accr[4] = {0,0,0,0}, acci[4] = {0,0,0,0};
  size_t wb = (((size_t)n * 32 + m) * 128 + i) * 128;
  for (int j = 0; j < 128; ++j){
    float wr = awr[wb + j], wi = awi[wb + j];
    #pragma unroll
    for (int b = 0; b < 4; ++b){
      accr[b] += wr * xr_s[b][j] - wi * xi_s[b][j];
      acci[b] += wr * xi_s[b][j] + wi * xr_s[b][j];
    }
  }
  #pragma unroll
  for (int b = 0; b < 4; ++b){
    float vr = accr[b], vi = acci[b];
    vr = vr > 0.01f ? vr - 0.01f : (vr < -0.01f ? vr + 0.01f : 0.0f);
    vi = vi > 0.01f ? vi - 0.01f : (vi < -0.01f ? vi + 0.01f : 0.0f);
    size_t dst = ((size_t)b * 32 + m) * 1024 + n * 128 + i;  // [b][m][d]
    Or[dst] = vr; Oi[dst] = vi;
  }
}

// ---------------- kernel D3: d-chunked irfft + residual in-place ----------------
__global__ __launch_bounds__(256) void kernelD3(const float* __restrict__ Or, const float* __restrict__ Oi,
    const float* __restrict__ ctab, const float* __restrict__ stab, float* __restrict__ y){
  __shared__ float cts[32][64], sts[32][64];
  __shared__ float Ors[32][144], Ois[32][144];
  int tid = threadIdx.x;
  int bx = blockIdx.x;
  int b = bx >> 9, tc = (bx >> 3) & 63, dc = bx & 7;
  int t0 = tc * 64, d0 = dc * 128;
  for (int i = 0; i < 8; ++i){
    int lin = i * 256 + tid;
    int m = lin >> 6, tl = lin & 63;
    float f = (m == 0 ? 1.0f : 2.0f) * 0.015625f;
    cts[m][tl] = ctab[m * 4096 + t0 + tl] * f;
    sts[m][tl] = stab[m * 4096 + t0 + tl] * f;
  }
  for (int i = 0; i < 4; ++i){
    int lin = i * 256 + tid;
    int m = lin >> 5, q = lin & 31;
    int w = q * 4;
    int ph = w + ((w >> 5) << 2);
    size_t src = ((size_t)b * 32 + m) * 1024 + d0 + w;
    *(f32x4*)&Ors[m][ph] = *(const f32x4*)&Or[src];
    *(f32x4*)&Ois[m][ph] = *(const f32x4*)&Oi[src];
  }
  __syncthreads();
  int tt = tid >> 4, dl = tid & 15;
  int wb0 = dl * 8;
  int ph0 = wb0 + ((wb0 >> 5) << 2);
  int ph1 = ph0 + 4;
  float acc[4][8];
  #pragma unroll
  for (int q = 0; q < 4; ++q)
    #pragma unroll
    for (int j = 0; j < 8; ++j) acc[q][j] = 0.f;
  for (int m = 0; m < 32; ++m){
    f32x4 cv = *(const f32x4*)&cts[m][tt * 4];
    f32x4 sv = *(const f32x4*)&sts[m][tt * 4];
    f32x4 orv0 = *(const f32x4*)&Ors[m][ph0];
    f32x4 orv1 = *(const f32x4*)&Ors[m][ph1];
    f32x4 oiv0 = *(const f32x4*)&Ois[m][ph0];
    f32x4 oiv1 = *(const f32x4*)&Ois[m][ph1];
    #pragma unroll
    for (int q = 0; q < 4; ++q){
      #pragma unroll
      for (int e = 0; e < 4; ++e){
        acc[q][e]     += cv[q] * orv0[e] - sv[q] * oiv0[e];
        acc[q][4 + e] += cv[q] * orv1[e] - sv[q] * oiv1[e];
      }
    }
  }
  #pragma unroll
  for (int q = 0; q < 4; ++q){
    size_t row = ((size_t)b * 4096 + t0 + tt * 4 + q) * 1024 + d0 + dl * 8;
    f32x4 r0 = *(const f32x4*)&y[row];
    f32x4 r1 = *(const f32x4*)&y[row + 4];
    #pragma unroll
    for (int e = 0; e < 4; ++e){ r0[e] += acc[q][e]; r1[e] += acc[q][4 + e]; }
    *(f32x4*)&y[row] = r0;
    *(f32x4*)&y[row + 4] = r1;
  }
}

// ---------------- LN1: y (f32) -> xln1 (bf16) ----------------
__global__ __launch_bounds__(256) void ln1_k(const float* __restrict__ y,
    const float* __restrict__ g, const float* __restrict__ bb, short* __restrict__ xln){
  size_t row = blockIdx.x;
  int tid = threadIdx.x;
  f32x4 v = *(const f32x4*)(y + row * 1024 + tid * 4);
  float sum = v[0] + v[1] + v[2] + v[3];
  float sq  = v[0]*v[0] + v[1]*v[1] + v[2]*v[2] + v[3]*v[3];
  for (int off = 32; off; off >>= 1){ sum += __shfl_down(sum, off); sq += __shfl_down(sq, off); }
  __shared__ float rs[4], rq[4];
  int lane = tid & 63, w = tid >> 6;
  if (lane == 0){ rs[w] = sum; rq[w] = sq; }
  __syncthreads();
  sum = rs[0] + rs[1] + rs[2] + rs[3]; sq = rq[0] + rq[1] + rq[2] + rq[3];
  float mu = sum * (1.0f / 1024.0f);
  float var = sq * (1.0f / 1024.0f) - mu * mu;
  float sc = rsqrtf(var + 1e-5f);
  s16x4 o;
  #pragma unroll
  for (int j = 0; j < 4; ++j){
    int d = tid * 4 + j;
    o[j] = f2bf((v[j] - mu) * sc * g[d] + bb[d]);
  }
  *(s16x4*)(xln + row * 1024 + tid * 4) = o;
}

// ---------------- m97-style 128^2 high-TLP bf16 MFMA GEMM ----------------
// 256 thr / 4 waves (2x2), BK=64 single-buffered 32KB LDS, 4 blocks/CU.
// mb-fast compact per-XCD band (r12 mapping). 0-conflict swizzle (r7-verified).
template<int EPI>
__global__ __launch_bounds__(256, 4) void gemm128_k(const short* __restrict__ A,
    const short* __restrict__ BT, const float* __restrict__ bias,
    const short* __restrict__ resid, short* __restrict__ Hout,
    float* __restrict__ Fout, int K, int N, int nMB, long row0_abs){
  __shared__ __align__(16) short As[8192];
  __shared__ __align__(16) short Bs[8192];
  const int tid = threadIdx.x;
  const int lane = tid & 63, wv = tid >> 6;
  const int wr = wv >> 1, wc = wv & 1;
  const int lr = lane & 15, lg = lane >> 4;

  // compact per-XCD band mapping (mb-fast, r12)
  const int xcd = blockIdx.x & 7, l = blockIdx.x >> 3;
  const int mband = nMB >> 3;
  const int mb = xcd * mband + (l % mband);
  const int nb = l / mband;
  const long arow0 = (long)mb * 128;
  const long bcol0 = (long)nb * 128;
  const int NT = K >> 6;

  const int rr = tid >> 3;
  const int sl8 = ((tid & 7) ^ (rr & 7)) * 8;
  const long aoff = (long)rr * K + sl8;
  const short* Au = A  + arow0 * K;
  const short* Bu = BT + bcol0 * K;
  const int ldsw = wv * 512;

  const int aR = (wr * 64 + lr) * 64;
  const int bR = (wc * 64 + lr) * 64;
  const int asl0 = ((lg)     ^ (lr & 7)) * 8;
  const int asl1 = ((4 + lg) ^ (lr & 7)) * 8;

  f32x4 acc[4][4] = {};

  for (int t = 0; t < NT; ++t){
    const long kof = (long)t * 64;
    #pragma unroll
    for (int u = 0; u < 4; ++u)
      gload16(Au + (long)(u * 32) * K + kof + aoff, As + u * 2048 + ldsw);
    #pragma unroll
    for (int u = 0; u < 4; ++u)
      gload16(Bu + (long)(u * 32) * K + kof + aoff, Bs + u * 2048 + ldsw);
    __syncthreads();
    #pragma unroll
    for (int ks = 0; ks < 2; ++ks){
      const int so = ks ? asl1 : asl0;
      s16x8 af[4], bf[4];
      #pragma unroll
      for (int mi = 0; mi < 4; ++mi) af[mi] = *(const s16x8*)&As[aR + mi * 1024 + so];
      #pragma unroll
      for (int ni = 0; ni < 4; ++ni) bf[ni] = *(const s16x8*)&Bs[bR + ni * 1024 + so];
      #pragma unroll
      for (int mi = 0; mi < 4; ++mi)
        #pragma unroll
        for (int ni = 0; ni < 4; ++ni)
          acc[mi][ni] = __builtin_amdgcn_mfma_f32_16x16x32_bf16(af[mi], bf[ni], acc[mi][ni], 0, 0, 0);
    }
    __syncthreads();
  }

  const int rb = lg * 4;
  #pragma unroll
  for (int mi = 0; mi < 4; ++mi){
    #pragma unroll
    for (int ni = 0; ni < 4; ++ni){
      int cl = (int)bcol0 + wc * 64 + ni * 16 + lr;
      float bv = bias[cl];
      #pragma unroll
      for (int i = 0; i < 4; ++i){
        long rl = arow0 + wr * 64 + mi * 16 + rb + i;
        float v = acc[mi][ni][i] + bv;
        if constexpr (EPI == 0){
          Hout[rl * (long)N + cl] = f2bf(gelu_f(v));
        } else {
          float rv = bf2f(resid[(row0_abs + rl) * 1024 + cl]);
          Fout[(row0_abs + rl) * 1024 + cl] = v + rv;
        }
      }
    }
  }
}

// ---------------- LN2 in-place on f32 out ----------------
__global__ __launch_bounds__(256) void ln2_k(float* __restrict__ out,
    const float* __restrict__ g, const float* __restrict__ bb){
  size_t row = blockIdx.x;
  int tid = threadIdx.x;
  float* p = out + row * 1024;
  f32x4 v = *(const f32x4*)(p + tid * 4);
  float sum = v[0] + v[1] + v[2] + v[3];
  float sq  = v[0]*v[0] + v[1]*v[1] + v[2]*v[2] + v[3]*v[3];
  for (int off = 32; off; off >>= 1){ sum += __shfl_down(sum, off); sq += __shfl_down(sq, off); }
  __shared__ float rs[4], rq[4];
  int lane = tid & 63, w = tid >> 6;
  if (lane == 0){ rs[w] = sum; rq[w] = sq; }
  __syncthreads();
  sum = rs[0] + rs[1] + rs[2] + rs[3]; sq = rq[0] + rq[1] + rq[2] + rq[3];
  float mu = sum * (1.0f / 1024.0f);
  float var = sq * (1.0f / 1024.0f) - mu * mu;
  float sc = rsqrtf(var + 1e-5f);
  f32x4 o;
  #pragma unroll
  for (int j = 0; j < 4; ++j){
    int d = tid * 4 + j;
    o[j] = (v[j] - mu) * sc * g[d] + bb[d];
  }
  *(f32x4*)(p + tid * 4) = o;
}

// ---------------- launch ----------------
extern "C" void kernel_launch(void* const* d_in, const int* in_sizes, int n_in,
                              void* d_out, int out_size, void* d_ws, size_t ws_size,
                              hipStream_t stream){
  (void)in_sizes; (void)n_in; (void)out_size;
  const int*   tokens = (const int*)d_in[0];
  const float* frw  = (const float*)d_in[1];
  const float* fiw  = (const float*)d_in[2];
  const float* mw   = (const float*)d_in[3];
  const float* po   = (const float*)d_in[4];
  const float* ftew = (const float*)d_in[5];
  const float* fteb = (const float*)d_in[6];
  const float* posph= (const float*)d_in[7];
  const float* awr  = (const float*)d_in[8];
  const float* awi  = (const float*)d_in[9];
  const float* ln1g = (const float*)d_in[10];
  const float* ln1b = (const float*)d_in[11];
  const float* w1   = (const float*)d_in[12];
  const float* b1   = (const float*)d_in[13];
  const float* w2   = (const float*)d_in[14];
  const float* b2   = (const float*)d_in[15];
  const float* ln2g = (const float*)d_in[16];
  const float* ln2b = (const float*)d_in[17];
  float* out = (float*)d_out;

  const size_t HB_BIG   = (size_t)16384 * 4096 * 2;   // 134.2 MB full-M hbuf
  const size_t HB_SMALL = (size_t)16384 * 1024 * 4;   // 67.1 MB (residual-sized)
  const size_t TAIL = (size_t)16384 * 1024 * 2        // xln1
                    + 2 * (size_t)4096 * 1024 * 2     // w1b, w2b
                    + 4 * 524288                      // ctab, stab, Or, Oi
                    + 2 * 4194304                     // Pr, Pi
                    + 512;                            // wcs
  const bool big = ws_size >= HB_BIG + TAIL;
  const size_t hb = big ? HB_BIG : HB_SMALL;

  char* ws = (char*)d_ws;
  size_t o = 0;
  float* residual = (float*)(ws + o); o += hb;        // head doubles as hbuf
  short* hbuf     = (short*)residual;
  short* xln1     = (short*)(ws + o); o += (size_t)16384 * 1024 * 2;
  short* w1b      = (short*)(ws + o); o += (size_t)4096 * 1024 * 2;
  short* w2b      = (short*)(ws + o); o += (size_t)4096 * 1024 * 2;
  float* ctab     = (float*)(ws + o); o += 524288;
  float* stab     = (float*)(ws + o); o += 524288;
  float* Or       = (float*)(ws + o); o += 524288;
  float* Oi       = (float*)(ws + o); o += 524288;
  float* Pr       = (float*)(ws + o); o += 4194304;
  float* Pi       = (float*)(ws + o); o += 4194304;
  float* wcs      = (float*)(ws + o); o += 512;

  prep_tab_k<<<512, 256, 0, stream>>>(ctab, stab, mw, po, wcs);
  transpose_bf16_k<<<dim3(64, 16), 256, 0, stream>>>(w1, w1b, 1024, 4096);
  transpose_bf16_k<<<dim3(16, 64), 256, 0, stream>>>(w2, w2b, 4096, 1024);

  kernelA3<<<2048, 256, 0, stream>>>(tokens, frw, fiw, wcs, ftew, fteb, posph, residual);
  kernelB2<<<1024, 256, 0, stream>>>(residual, Pr, Pi);
  kernelC2<<<256, 128, 0, stream>>>(Pr, Pi, awr, awi, Or, Oi);
  kernelD3<<<2048, 256, 0, stream>>>(Or, Oi, ctab, stab, residual);
  ln1_k<<<16384, 256, 0, stream>>>(residual, ln1g, ln1b, xln1);

  if (big){
    gemm128_k<0><<<4096, 256, 0, stream>>>(xln1, w1b, b1, nullptr, hbuf, nullptr,
                                           1024, 4096, 128, 0);
    gemm128_k<1><<<1024, 256, 0, stream>>>(hbuf, w2b, b2, xln1, nullptr, out,
                                           4096, 1024, 128, 0);
  } else {
    for (int c = 0; c < 2; ++c){
      long row0 = (long)c * 8192;
      gemm128_k<0><<<2048, 256, 0, stream>>>(xln1 + row0 * 1024, w1b, b1, nullptr,
                                             hbuf, nullptr, 1024, 4096, 64, 0);
      gemm128_k<1><<<512, 256, 0, stream>>>(hbuf, w2b, b2, xln1, nullptr, out,
                                            4096, 1024, 64, row0);
    }
  }
  ln2_k<<<16384, 256, 0, stream>>>(out, ln2g, ln2b);
}